// Round 16
// baseline (159.776 us; speedup 1.0000x reference)
//
#include <hip/hip_runtime.h>
#include <hip/hip_bf16.h>

typedef __bf16 bf16_t;
typedef __bf16 bf16x8 __attribute__((ext_vector_type(8)));
typedef __bf16 bf16x4 __attribute__((ext_vector_type(4)));
typedef float f32x4 __attribute__((ext_vector_type(4)));

#define MFMA16(a, b, c) __builtin_amdgcn_mfma_f32_16x16x32_bf16((a), (b), (c), 0, 0, 0)

__device__ __forceinline__ f32x4 v4zero() {
  f32x4 z = {0.f, 0.f, 0.f, 0.f};
  return z;
}

// window-partition row mapping: m = win*512 + t  ->  row in x [B*4096]
__device__ __forceinline__ int xrow_of(int m) {
  int win = m >> 9, t = m & 511;
  int b = win >> 3, d1 = (win >> 2) & 1, h1 = (win >> 1) & 1, w1 = win & 1;
  int d2 = t >> 6, h2 = (t >> 3) & 7, w2 = t & 7;
  return (b << 12) | ((d1 * 8 + d2) << 8) | ((h1 * 8 + h2) << 4) | (w1 * 8 + w2);
}

// ---------------- kernel 1: QKV projection, depth-3 pipeline ----------------
// grid (128, 9), block 256. One output type per block (n0/384).
__global__ __launch_bounds__(256) void qkv_kernel(
    const float* __restrict__ x, const float* __restrict__ w,
    const float* __restrict__ bias, bf16_t* __restrict__ qg,
    bf16_t* __restrict__ kg, bf16_t* __restrict__ vtg) {
  __shared__ __align__(16) char smem[40960];
  bf16_t(*As)[128][40] = (bf16_t(*)[128][40])smem;            // [2][128][40]
  bf16_t(*Bs)[128][40] = (bf16_t(*)[128][40])(smem + 20480);  // [2][128][40]
  bf16_t(*Csh)[136] = (bf16_t(*)[136])smem;                   // epilogue overlay

  const int tid = threadIdx.x;
  const int lane = tid & 63, wv = tid >> 6;
  const int m0 = blockIdx.x * 128, n0 = blockIdx.y * 128;

  const int arow = tid >> 1, aseg = tid & 1;
  const float* asrc = x + (size_t)xrow_of(m0 + arow) * 384 + aseg * 16;
  const int bn = tid & 127, bks = (tid >> 7) * 16;
  const float* bsrc = w + (size_t)bks * 1152 + n0 + bn;

  const int wr = (wv >> 1) * 64, wc = (wv & 1) * 64;
  const int lr = lane & 15, lg = lane >> 4, lk = lg * 8;

  f32x4 acc[4][4];
#pragma unroll
  for (int fr = 0; fr < 4; ++fr)
#pragma unroll
    for (int fc = 0; fc < 4; ++fc) acc[fr][fc] = v4zero();

  // two in-flight register sets (depth-3 pipeline): tile t lives in set t&1
  f32x4 afr[2][4];
  float bfr[2][16];

#define LOAD_TILE(kt, s)                                           \
  {                                                                \
    _Pragma("unroll") for (int i = 0; i < 4; ++i)                  \
        afr[s][i] = *(const f32x4*)(asrc + (kt)*32 + i * 4);       \
    _Pragma("unroll") for (int i = 0; i < 16; ++i)                 \
        bfr[s][i] = bsrc[(size_t)((kt)*32 + i) * 1152];            \
  }

#define STAGE_TILE(s, buf)                                         \
  {                                                                \
    bf16x8 a0, a1, b0, b1;                                         \
    _Pragma("unroll") for (int i = 0; i < 4; ++i) {                \
      a0[i] = (bf16_t)afr[s][0][i];                                \
      a0[4 + i] = (bf16_t)afr[s][1][i];                            \
      a1[i] = (bf16_t)afr[s][2][i];                                \
      a1[4 + i] = (bf16_t)afr[s][3][i];                            \
    }                                                              \
    _Pragma("unroll") for (int i = 0; i < 8; ++i) {                \
      b0[i] = (bf16_t)bfr[s][i];                                   \
      b1[i] = (bf16_t)bfr[s][8 + i];                               \
    }                                                              \
    *(bf16x8*)&As[buf][arow][aseg * 16] = a0;                      \
    *(bf16x8*)&As[buf][arow][aseg * 16 + 8] = a1;                  \
    *(bf16x8*)&Bs[buf][bn][bks] = b0;                              \
    *(bf16x8*)&Bs[buf][bn][bks + 8] = b1;                          \
  }

  LOAD_TILE(0, 0);
  LOAD_TILE(1, 1);
  STAGE_TILE(0, 0);
  LOAD_TILE(2, 0);
  __syncthreads();

  for (int kt = 0; kt < 12; ++kt) {
    const int cur = kt & 1;
    bf16x8 af[4], bfv[4];
#pragma unroll
    for (int fr = 0; fr < 4; ++fr) af[fr] = *(const bf16x8*)&As[cur][wr + fr * 16 + lr][lk];
#pragma unroll
    for (int fc = 0; fc < 4; ++fc) bfv[fc] = *(const bf16x8*)&Bs[cur][wc + fc * 16 + lr][lk];
#pragma unroll
    for (int fr = 0; fr < 4; ++fr)
#pragma unroll
      for (int fc = 0; fc < 4; ++fc)
        acc[fr][fc] = MFMA16(af[fr], bfv[fc], acc[fr][fc]);
    if (kt < 11) {
      STAGE_TILE((kt + 1) & 1, cur ^ 1);  // stage tile kt+1 (loaded at kt-2)
      if (kt < 9) LOAD_TILE(kt + 3, (kt + 3) & 1);
    }
    __syncthreads();
  }
#undef LOAD_TILE
#undef STAGE_TILE

  const int type = n0 / 384;
  if (type == 2) {
    // V: store transposed [64][512], direct bf16x4 (t-contiguous)
#pragma unroll
    for (int fc = 0; fc < 4; ++fc) {
      const int col = n0 + wc + fc * 16 + lr;
      const float bc = bias[col];
      const int cc = col - 768, hh = cc >> 6, c = cc & 63;
#pragma unroll
      for (int fr = 0; fr < 4; ++fr) {
        const int m = m0 + wr + fr * 16 + lg * 4;
        const int win = m >> 9, t = m & 511;
        bf16x4 pk;
#pragma unroll
        for (int r = 0; r < 4; ++r) pk[r] = (bf16_t)(acc[fr][fc][r] + bc);
        *(bf16x4*)(vtg + ((size_t)(win * 6 + hh) * 64 + c) * 512 + t) = pk;
      }
    }
  } else {
    // Q/K: transpose through LDS, write coalesced bf16x8 rows
#pragma unroll
    for (int fc = 0; fc < 4; ++fc) {
      const int col = n0 + wc + fc * 16 + lr;
      const float bc = bias[col];
#pragma unroll
      for (int fr = 0; fr < 4; ++fr)
#pragma unroll
        for (int r = 0; r < 4; ++r)
          Csh[wr + fr * 16 + lg * 4 + r][wc + fc * 16 + lr] = (bf16_t)(acc[fr][fc][r] + bc);
    }
    __syncthreads();
    const int mloc = tid >> 1, half = tid & 1;
    const int hh2 = ((n0 - type * 384) >> 6) + half;
    const int m = m0 + mloc, win = m >> 9, t = m & 511;
    bf16_t* dst = (type == 0 ? qg : kg) + ((size_t)(win * 6 + hh2) * 512 + t) * 64;
#pragma unroll
    for (int j = 0; j < 8; ++j)
      *(bf16x8*)(dst + j * 8) = *(const bf16x8*)&Csh[mloc][half * 64 + j * 8];
  }
}

// ---------------- kernel 2: attention (unchanged from round 15) -------------
__global__ __launch_bounds__(256) void attn_kernel(
    const bf16_t* __restrict__ qg, const bf16_t* __restrict__ kg,
    const bf16_t* __restrict__ vtg, const float* __restrict__ rpx,
    const float* __restrict__ rpy, const float* __restrict__ rpz,
    bf16_t* __restrict__ ao) {
  __shared__ __align__(16) char smem[32768];   // phase union
  __shared__ __align__(16) float rxT[8][132];  // persistent rx strip
  const int tid = threadIdx.x, lane = tid & 63, wv = tid >> 6;
  const int hh = blockIdx.x, win = blockIdx.y, qt = blockIdx.z;
  const int wh = win * 6 + hh;
  const bf16_t* Qb = qg + (size_t)wh * 32768 + (size_t)qt * 8192;
  const bf16_t* Kb = kg + (size_t)wh * 32768;
  const bf16_t* Vb = vtg + (size_t)wh * 32768;  // transposed [64][512]

  bf16_t(*Qsh)[68] = (bf16_t(*)[68])smem;
  bf16_t(*Rsh)[68] = (bf16_t(*)[68])(smem + 17408);
  float(*Gsh)[132] = (float(*)[132])smem;
  bf16_t(*Ksh)[64][64] = (bf16_t(*)[64][64])smem;
  bf16_t(*Vsh)[64][64] = (bf16_t(*)[64][64])(smem + 16384);

  for (int i = tid; i < 1024; i += 256) {
    int row = i >> 3, slot = i & 7;
    *(bf16x8*)&Qsh[row][slot * 8] = *(const bf16x8*)(Qb + row * 64 + slot * 8);
  }
  for (int i = tid; i < 360; i += 256) {
    int row = i >> 3, slot = i & 7;
    int axis = row / 15, j = row - axis * 15;
    const float* RP = (axis == 0) ? rpx : (axis == 1) ? rpy : rpz;
    f32x4 r0 = *(const f32x4*)(RP + j * 64 + slot * 8);
    f32x4 r1 = *(const f32x4*)(RP + j * 64 + slot * 8 + 4);
    bf16x8 p;
#pragma unroll
    for (int jj = 0; jj < 4; ++jj) {
      p[jj] = (bf16_t)r0[jj];
      p[4 + jj] = (bf16_t)r1[jj];
    }
    *(bf16x8*)&Rsh[row][slot * 8] = p;
  }
  bf16x8 kreg[2], vreg[2];
#pragma unroll
  for (int r = 0; r < 2; ++r) {
    int ci = r * 256 + tid, row = ci >> 3, slot = ci & 7;
    kreg[r] = *(const bf16x8*)(Kb + (size_t)row * 64 + slot * 8);
    vreg[r] = *(const bf16x8*)(Vb + (size_t)row * 512 + slot * 8);
  }
  __syncthreads();

  const int lr = lane & 15, lg = lane >> 4;
  const int qrow0 = qt * 128 + wv * 32;
  const int qrb = wv * 32 + lr;

  bf16x8 bq[2][2];
#pragma unroll
  for (int fq = 0; fq < 2; ++fq)
#pragma unroll
    for (int ks = 0; ks < 2; ++ks)
      bq[fq][ks] = *(const bf16x8*)&Qsh[wv * 32 + fq * 16 + lr][ks * 32 + lg * 8];

  bf16x8 br[3][2];
#pragma unroll
  for (int jt = 0; jt < 3; ++jt)
#pragma unroll
    for (int ks = 0; ks < 2; ++ks)
      br[jt][ks] = *(const bf16x8*)&Rsh[jt * 16 + lr][ks * 32 + lg * 8];

  f32x4 gacc[2][3];
#pragma unroll
  for (int fq = 0; fq < 2; ++fq)
#pragma unroll
    for (int jt = 0; jt < 3; ++jt) {
      f32x4 g = MFMA16(bq[fq][0], br[jt][0], v4zero());
      gacc[fq][jt] = MFMA16(bq[fq][1], br[jt][1], g);
    }
  __syncthreads();

#pragma unroll
  for (int fq = 0; fq < 2; ++fq)
#pragma unroll
    for (int jt = 0; jt < 3; ++jt)
#pragma unroll
      for (int r = 0; r < 4; ++r)
        Gsh[jt * 16 + lr][(wv * 2 + fq) * 16 + lg * 4 + r] = gacc[fq][jt][r];
  __syncthreads();

  f32x4 byz[2][4];
#pragma unroll
  for (int fq = 0; fq < 2; ++fq) {
    const int q_r = qrb + fq * 16;
    const int qh_ = (q_r >> 3) & 7, qw_ = q_r & 7, qd_ = qt * 2 + (q_r >> 6);
#pragma unroll
    for (int fk = 0; fk < 4; ++fk) {
      f32x4 v;
#pragma unroll
      for (int i = 0; i < 4; ++i) {
        int kkl = fk * 16 + lg * 4 + i;
        v[i] = Gsh[15 + qh_ - (kkl >> 3) + 7][q_r] + Gsh[30 + qw_ - (kkl & 7) + 7][q_r];
      }
      byz[fq][fk] = v;
    }
    if (lg == 0) {
#pragma unroll
      for (int kt = 0; kt < 8; ++kt) rxT[kt][q_r] = Gsh[qd_ - kt + 7][q_r];
    }
  }
  __syncthreads();

#pragma unroll
  for (int r = 0; r < 2; ++r) {
    int ci = r * 256 + tid, row = ci >> 3, slot = ci & 7;
    *(bf16x8*)&Ksh[0][row][(slot ^ (row & 7)) * 8] = kreg[r];
    *(bf16x8*)&Vsh[0][row][(slot ^ (row & 7)) * 8] = vreg[r];
    kreg[r] = *(const bf16x8*)(Kb + (size_t)(64 + row) * 64 + slot * 8);
    vreg[r] = *(const bf16x8*)(Vb + (size_t)row * 512 + 64 + slot * 8);
  }
  __syncthreads();

  float rsum[2] = {0.f, 0.f};
  f32x4 oacc[2][4];
#pragma unroll
  for (int fq = 0; fq < 2; ++fq)
#pragma unroll
    for (int fc = 0; fc < 4; ++fc) oacc[fq][fc] = v4zero();

  for (int kt = 0; kt < 8; ++kt) {
    const int cur = kt & 1;
    bf16x8 ak[4][2];
#pragma unroll
    for (int fk = 0; fk < 4; ++fk) {
      const int row = fk * 16 + lr;
#pragma unroll
      for (int ks = 0; ks < 2; ++ks)
        ak[fk][ks] = *(const bf16x8*)&Ksh[cur][row][((ks * 4 + lg) ^ (row & 7)) * 8];
    }

    f32x4 sb[2][4];
#pragma unroll
    for (int fq = 0; fq < 2; ++fq) {
      const float rx = rxT[kt][qrb + fq * 16];
#pragma unroll
      for (int fk = 0; fk < 4; ++fk) {
        f32x4 s = MFMA16(ak[fk][0], bq[fq][0], v4zero());
        s = MFMA16(ak[fk][1], bq[fq][1], s);
        sb[fq][fk] = s * 0.125f + rx + byz[fq][fk];
      }
    }

#pragma unroll
    for (int fq = 0; fq < 2; ++fq) {
      float rs = 0.f;
#pragma unroll
      for (int fk = 0; fk < 4; ++fk)
#pragma unroll
        for (int i = 0; i < 4; ++i) {
          float p = __expf(sb[fq][fk][i]);
          sb[fq][fk][i] = p;
          rs += p;
        }
      rsum[fq] += rs;
    }

    bf16x8 pa[2][2];
#pragma unroll
    for (int fq = 0; fq < 2; ++fq)
#pragma unroll
      for (int h = 0; h < 2; ++h) {
#pragma unroll
        for (int j = 0; j < 4; ++j) {
          pa[fq][h][j] = (bf16_t)sb[fq][2 * h][j];
          pa[fq][h][4 + j] = (bf16_t)sb[fq][2 * h + 1][j];
        }
      }

#pragma unroll
    for (int h = 0; h < 2; ++h)
#pragma unroll
      for (int fc2 = 0; fc2 < 4; ++fc2) {
        const int row = fc2 * 16 + lr;
        const int c0 = (((h * 4 + (lg >> 1)) ^ (row & 7)) * 8) + (lg & 1) * 4;
        const int c1 = (((h * 4 + 2 + (lg >> 1)) ^ (row & 7)) * 8) + (lg & 1) * 4;
        bf16x4 v0 = *(const bf16x4*)&Vsh[cur][row][c0];
        bf16x4 v1 = *(const bf16x4*)&Vsh[cur][row][c1];
        bf16x8 bv;
#pragma unroll
        for (int j = 0; j < 4; ++j) {
          bv[j] = v0[j];
          bv[4 + j] = v1[j];
        }
#pragma unroll
        for (int fq = 0; fq < 2; ++fq)
          oacc[fq][fc2] = MFMA16(pa[fq][h], bv, oacc[fq][fc2]);
      }

    if (kt < 7) {
#pragma unroll
      for (int r = 0; r < 2; ++r) {
        int ci = r * 256 + tid, row = ci >> 3, slot = ci & 7;
        *(bf16x8*)&Ksh[cur ^ 1][row][(slot ^ (row & 7)) * 8] = kreg[r];
        *(bf16x8*)&Vsh[cur ^ 1][row][(slot ^ (row & 7)) * 8] = vreg[r];
        if (kt < 6) {
          kreg[r] = *(const bf16x8*)(Kb + (size_t)((kt + 2) * 64 + row) * 64 + slot * 8);
          vreg[r] = *(const bf16x8*)(Vb + (size_t)row * 512 + (kt + 2) * 64 + slot * 8);
        }
      }
    }
    __syncthreads();
  }

#pragma unroll
  for (int fq = 0; fq < 2; ++fq) {
    rsum[fq] += __shfl_xor(rsum[fq], 16);
    rsum[fq] += __shfl_xor(rsum[fq], 32);
  }
  f32x4 linv[2];
#pragma unroll
  for (int fq = 0; fq < 2; ++fq)
#pragma unroll
    for (int i = 0; i < 4; ++i)
      linv[fq][i] = 1.0f / __shfl(rsum[fq], lg * 4 + i);

#pragma unroll
  for (int fq = 0; fq < 2; ++fq)
#pragma unroll
    for (int fc2 = 0; fc2 < 4; ++fc2) {
      size_t base = ((size_t)win * 512 + qrow0 + fq * 16 + lg * 4) * 384 + hh * 64 + fc2 * 16 + lr;
#pragma unroll
      for (int i = 0; i < 4; ++i)
        ao[base + (size_t)i * 384] = (bf16_t)(oacc[fq][fc2][i] * linv[fq][i]);
    }
}

// ---------------- kernel 3: output projection, depth-2 dbuf -----------------
__global__ __launch_bounds__(256) void proj_kernel(
    const bf16_t* __restrict__ ain, const float* __restrict__ w,
    const float* __restrict__ bias, float* __restrict__ out) {
  __shared__ __align__(16) char smem[40960];
  bf16_t(*As)[128][40] = (bf16_t(*)[128][40])smem;
  bf16_t(*Bs)[128][40] = (bf16_t(*)[128][40])(smem + 20480);

  const int tid = threadIdx.x;
  const int lane = tid & 63, wv = tid >> 6;
  const int m0 = blockIdx.x * 128, n0 = blockIdx.y * 128;

  const int arow = tid >> 1, aseg = tid & 1;
  const bf16_t* asrc = ain + (size_t)(m0 + arow) * 384 + aseg * 16;
  const int bn = tid & 127, bks = (tid >> 7) * 16;
  const float* bsrc = w + (size_t)bks * 384 + n0 + bn;

  const int wr = (wv >> 1) * 64, wc = (wv & 1) * 64;
  const int lr = lane & 15, lk = (lane >> 4) * 8;

  f32x4 acc[4][4];
#pragma unroll
  for (int fr = 0; fr < 4; ++fr)
#pragma unroll
    for (int fc = 0; fc < 4; ++fc) acc[fr][fc] = v4zero();

  bf16x8 a0r, a1r;
  float bfr[16];

#define PLOAD(kt)                                                  \
  {                                                                \
    a0r = *(const bf16x8*)(asrc + (kt)*32);                        \
    a1r = *(const bf16x8*)(asrc + (kt)*32 + 8);                    \
    _Pragma("unroll") for (int i = 0; i < 16; ++i)                 \
        bfr[i] = bsrc[(size_t)((kt)*32 + i) * 384];                \
  }

#define PSTAGE(buf)                                                \
  {                                                                \
    bf16x8 b0, b1;                                                 \
    _Pragma("unroll") for (int i = 0; i < 8; ++i) {                \
      b0[i] = (bf16_t)bfr[i];                                      \
      b1[i] = (bf16_t)bfr[8 + i];                                  \
    }                                                              \
    *(bf16x8*)&As[buf][arow][aseg * 16] = a0r;                     \
    *(bf16x8*)&As[buf][arow][aseg * 16 + 8] = a1r;                 \
    *(bf16x8*)&Bs[buf][bn][bks] = b0;                              \
    *(bf16x8*)&Bs[buf][bn][bks + 8] = b1;                          \
  }

  PLOAD(0);
  PSTAGE(0);
  PLOAD(1);
  __syncthreads();

  for (int kt = 0; kt < 12; ++kt) {
    const int cur = kt & 1;
    bf16x8 af[4], bfv[4];
#pragma unroll
    for (int fr = 0; fr < 4; ++fr) af[fr] = *(const bf16x8*)&As[cur][wr + fr * 16 + lr][lk];
#pragma unroll
    for (int fc = 0; fc < 4; ++fc) bfv[fc] = *(const bf16x8*)&Bs[cur][wc + fc * 16 + lr][lk];
#pragma unroll
    for (int fr = 0; fr < 4; ++fr)
#pragma unroll
      for (int fc = 0; fc < 4; ++fc)
        acc[fr][fc] = MFMA16(af[fr], bfv[fc], acc[fr][fc]);
    if (kt < 11) {
      PSTAGE(cur ^ 1);
      if (kt < 10) PLOAD(kt + 2);
    }
    __syncthreads();
  }
#undef PLOAD
#undef PSTAGE

#pragma unroll
  for (int fc = 0; fc < 4; ++fc) {
    const int col = n0 + wc + fc * 16 + lr;
    const float bc = bias[col];
#pragma unroll
    for (int fr = 0; fr < 4; ++fr) {
      const int m = m0 + wr + fr * 16 + (lane >> 4) * 4;
#pragma unroll
      for (int r = 0; r < 4; ++r)
        out[(size_t)xrow_of(m + r) * 384 + col] = acc[fr][fc][r] + bc;
    }
  }
}

extern "C" void kernel_launch(void* const* d_in, const int* in_sizes, int n_in,
                              void* d_out, int out_size, void* d_ws, size_t ws_size,
                              hipStream_t stream) {
  (void)in_sizes; (void)n_in; (void)out_size;
  const float* x = (const float*)d_in[0];
  const float* qkv_w = (const float*)d_in[1];
  const float* qkv_b = (const float*)d_in[2];
  const float* proj_w = (const float*)d_in[3];
  const float* proj_b = (const float*)d_in[4];
  const float* rpx = (const float*)d_in[5];
  const float* rpy = (const float*)d_in[6];
  const float* rpz = (const float*)d_in[7];
  float* out = (float*)d_out;

  const size_t NE = 6291456;  // 32*6*512*64 = 16384*384
  if (ws_size < NE * 4 * sizeof(bf16_t)) return;
  bf16_t* qg = (bf16_t*)d_ws;
  bf16_t* kg = qg + NE;
  bf16_t* vtg = kg + NE;
  bf16_t* ao = vtg + NE;

  qkv_kernel<<<dim3(128, 9), 256, 0, stream>>>(x, qkv_w, qkv_b, qg, kg, vtg);
  attn_kernel<<<dim3(6, 32, 4), 256, 0, stream>>>(qg, kg, vtg, rpx, rpy, rpz, ao);
  proj_kernel<<<dim3(128, 3), 256, 0, stream>>>(ao, proj_w, proj_b, out);
}

// Round 17
// 94.189 us; speedup vs baseline: 1.6963x; 1.6963x over previous
//
#include <hip/hip_runtime.h>
#include <hip/hip_bf16.h>

typedef __bf16 bf16_t;
typedef __bf16 bf16x8 __attribute__((ext_vector_type(8)));
typedef __bf16 bf16x4 __attribute__((ext_vector_type(4)));
typedef float f32x4 __attribute__((ext_vector_type(4)));

#define MFMA16(a, b, c) __builtin_amdgcn_mfma_f32_16x16x32_bf16((a), (b), (c), 0, 0, 0)

__device__ __forceinline__ f32x4 v4zero() {
  f32x4 z = {0.f, 0.f, 0.f, 0.f};
  return z;
}

// window-partition row mapping: m = win*512 + t  ->  row in x [B*4096]
__device__ __forceinline__ int xrow_of(int m) {
  int win = m >> 9, t = m & 511;
  int b = win >> 3, d1 = (win >> 2) & 1, h1 = (win >> 1) & 1, w1 = win & 1;
  int d2 = t >> 6, h2 = (t >> 3) & 7, w2 = t & 7;
  return (b << 12) | ((d1 * 8 + d2) << 8) | ((h1 * 8 + h2) << 4) | (w1 * 8 + w2);
}

// ---------------- kernel 1: QKV projection, depth-3, NAMED register sets ----
// grid (128, 9), block 256. Rule #20 fix: all staging regs statically indexed.
__global__ __launch_bounds__(256) void qkv_kernel(
    const float* __restrict__ x, const float* __restrict__ w,
    const float* __restrict__ bias, bf16_t* __restrict__ qg,
    bf16_t* __restrict__ kg, bf16_t* __restrict__ vtg) {
  __shared__ __align__(16) char smem[40960];
  bf16_t(*As)[128][40] = (bf16_t(*)[128][40])smem;            // [2][128][40]
  bf16_t(*Bs)[128][40] = (bf16_t(*)[128][40])(smem + 20480);  // [2][128][40]
  bf16_t(*Csh)[136] = (bf16_t(*)[136])smem;                   // epilogue overlay

  const int tid = threadIdx.x;
  const int lane = tid & 63, wv = tid >> 6;
  const int m0 = blockIdx.x * 128, n0 = blockIdx.y * 128;

  const int arow = tid >> 1, aseg = tid & 1;
  const float* asrc = x + (size_t)xrow_of(m0 + arow) * 384 + aseg * 16;
  const int bn = tid & 127, bks = (tid >> 7) * 16;
  const float* bsrc = w + (size_t)bks * 1152 + n0 + bn;

  const int wr = (wv >> 1) * 64, wc = (wv & 1) * 64;
  const int lr = lane & 15, lg = lane >> 4, lk = lg * 8;

  f32x4 acc[4][4];
#pragma unroll
  for (int fr = 0; fr < 4; ++fr)
#pragma unroll
    for (int fc = 0; fc < 4; ++fc) acc[fr][fc] = v4zero();

  // named register sets: A holds even tiles, B holds odd tiles
  f32x4 afrA[4], afrB[4];
  float bfrA[16], bfrB[16];

#define LOAD_SET(kt, AF, BF)                                       \
  {                                                                \
    _Pragma("unroll") for (int i = 0; i < 4; ++i)                  \
        AF[i] = *(const f32x4*)(asrc + (kt)*32 + i * 4);           \
    _Pragma("unroll") for (int i = 0; i < 16; ++i)                 \
        BF[i] = bsrc[(size_t)((kt)*32 + i) * 1152];                \
  }

#define STAGE_SET(AF, BF, buf)                                     \
  {                                                                \
    bf16x8 a0, a1, b0, b1;                                         \
    _Pragma("unroll") for (int i = 0; i < 4; ++i) {                \
      a0[i] = (bf16_t)AF[0][i];                                    \
      a0[4 + i] = (bf16_t)AF[1][i];                                \
      a1[i] = (bf16_t)AF[2][i];                                    \
      a1[4 + i] = (bf16_t)AF[3][i];                                \
    }                                                              \
    _Pragma("unroll") for (int i = 0; i < 8; ++i) {                \
      b0[i] = (bf16_t)BF[i];                                       \
      b1[i] = (bf16_t)BF[8 + i];                                   \
    }                                                              \
    *(bf16x8*)&As[buf][arow][aseg * 16] = a0;                      \
    *(bf16x8*)&As[buf][arow][aseg * 16 + 8] = a1;                  \
    *(bf16x8*)&Bs[buf][bn][bks] = b0;                              \
    *(bf16x8*)&Bs[buf][bn][bks + 8] = b1;                          \
  }

#define DO_MFMA(buf)                                                        \
  {                                                                         \
    bf16x8 af[4], bfv[4];                                                   \
    _Pragma("unroll") for (int fr = 0; fr < 4; ++fr)                        \
        af[fr] = *(const bf16x8*)&As[buf][wr + fr * 16 + lr][lk];           \
    _Pragma("unroll") for (int fc = 0; fc < 4; ++fc)                        \
        bfv[fc] = *(const bf16x8*)&Bs[buf][wc + fc * 16 + lr][lk];          \
    _Pragma("unroll") for (int fr = 0; fr < 4; ++fr)                        \
        _Pragma("unroll") for (int fc = 0; fc < 4; ++fc)                    \
            acc[fr][fc] = MFMA16(af[fr], bfv[fc], acc[fr][fc]);             \
  }

  LOAD_SET(0, afrA, bfrA);
  LOAD_SET(1, afrB, bfrB);
  STAGE_SET(afrA, bfrA, 0);
  LOAD_SET(2, afrA, bfrA);
  __syncthreads();

  for (int j = 0; j < 6; ++j) {
    // even step kt = 2j (buf 0)
    DO_MFMA(0);
    if (2 * j < 11) STAGE_SET(afrB, bfrB, 1);        // tile 2j+1 (loaded at kt-2)
    if (2 * j < 9) LOAD_SET(2 * j + 3, afrB, bfrB);  // tile 2j+3
    __syncthreads();
    // odd step kt = 2j+1 (buf 1)
    DO_MFMA(1);
    if (2 * j + 1 < 11) STAGE_SET(afrA, bfrA, 0);        // tile 2j+2
    if (2 * j + 1 < 9) LOAD_SET(2 * j + 4, afrA, bfrA);  // tile 2j+4
    __syncthreads();
  }
#undef LOAD_SET
#undef STAGE_SET
#undef DO_MFMA

  const int type = n0 / 384;
  if (type == 2) {
    // V: store transposed [64][512], direct bf16x4 (t-contiguous)
#pragma unroll
    for (int fc = 0; fc < 4; ++fc) {
      const int col = n0 + wc + fc * 16 + lr;
      const float bc = bias[col];
      const int cc = col - 768, hh = cc >> 6, c = cc & 63;
#pragma unroll
      for (int fr = 0; fr < 4; ++fr) {
        const int m = m0 + wr + fr * 16 + lg * 4;
        const int win = m >> 9, t = m & 511;
        bf16x4 pk;
#pragma unroll
        for (int r = 0; r < 4; ++r) pk[r] = (bf16_t)(acc[fr][fc][r] + bc);
        *(bf16x4*)(vtg + ((size_t)(win * 6 + hh) * 64 + c) * 512 + t) = pk;
      }
    }
  } else {
    // Q/K: transpose through LDS, write coalesced bf16x8 rows
#pragma unroll
    for (int fc = 0; fc < 4; ++fc) {
      const int col = n0 + wc + fc * 16 + lr;
      const float bc = bias[col];
#pragma unroll
      for (int fr = 0; fr < 4; ++fr)
#pragma unroll
        for (int r = 0; r < 4; ++r)
          Csh[wr + fr * 16 + lg * 4 + r][wc + fc * 16 + lr] = (bf16_t)(acc[fr][fc][r] + bc);
    }
    __syncthreads();
    const int mloc = tid >> 1, half = tid & 1;
    const int hh2 = ((n0 - type * 384) >> 6) + half;
    const int m = m0 + mloc, win = m >> 9, t = m & 511;
    bf16_t* dst = (type == 0 ? qg : kg) + ((size_t)(win * 6 + hh2) * 512 + t) * 64;
#pragma unroll
    for (int j = 0; j < 8; ++j)
      *(bf16x8*)(dst + j * 8) = *(const bf16x8*)&Csh[mloc][half * 64 + j * 8];
  }
}

// ---------------- kernel 2: attention (unchanged) ---------------------------
__global__ __launch_bounds__(256) void attn_kernel(
    const bf16_t* __restrict__ qg, const bf16_t* __restrict__ kg,
    const bf16_t* __restrict__ vtg, const float* __restrict__ rpx,
    const float* __restrict__ rpy, const float* __restrict__ rpz,
    bf16_t* __restrict__ ao) {
  __shared__ __align__(16) char smem[32768];   // phase union
  __shared__ __align__(16) float rxT[8][132];  // persistent rx strip
  const int tid = threadIdx.x, lane = tid & 63, wv = tid >> 6;
  const int hh = blockIdx.x, win = blockIdx.y, qt = blockIdx.z;
  const int wh = win * 6 + hh;
  const bf16_t* Qb = qg + (size_t)wh * 32768 + (size_t)qt * 8192;
  const bf16_t* Kb = kg + (size_t)wh * 32768;
  const bf16_t* Vb = vtg + (size_t)wh * 32768;  // transposed [64][512]

  bf16_t(*Qsh)[68] = (bf16_t(*)[68])smem;
  bf16_t(*Rsh)[68] = (bf16_t(*)[68])(smem + 17408);
  float(*Gsh)[132] = (float(*)[132])smem;
  bf16_t(*Ksh)[64][64] = (bf16_t(*)[64][64])smem;
  bf16_t(*Vsh)[64][64] = (bf16_t(*)[64][64])(smem + 16384);

  for (int i = tid; i < 1024; i += 256) {
    int row = i >> 3, slot = i & 7;
    *(bf16x8*)&Qsh[row][slot * 8] = *(const bf16x8*)(Qb + row * 64 + slot * 8);
  }
  for (int i = tid; i < 360; i += 256) {
    int row = i >> 3, slot = i & 7;
    int axis = row / 15, j = row - axis * 15;
    const float* RP = (axis == 0) ? rpx : (axis == 1) ? rpy : rpz;
    f32x4 r0 = *(const f32x4*)(RP + j * 64 + slot * 8);
    f32x4 r1 = *(const f32x4*)(RP + j * 64 + slot * 8 + 4);
    bf16x8 p;
#pragma unroll
    for (int jj = 0; jj < 4; ++jj) {
      p[jj] = (bf16_t)r0[jj];
      p[4 + jj] = (bf16_t)r1[jj];
    }
    *(bf16x8*)&Rsh[row][slot * 8] = p;
  }
  bf16x8 kreg[2], vreg[2];
#pragma unroll
  for (int r = 0; r < 2; ++r) {
    int ci = r * 256 + tid, row = ci >> 3, slot = ci & 7;
    kreg[r] = *(const bf16x8*)(Kb + (size_t)row * 64 + slot * 8);
    vreg[r] = *(const bf16x8*)(Vb + (size_t)row * 512 + slot * 8);
  }
  __syncthreads();

  const int lr = lane & 15, lg = lane >> 4;
  const int qrow0 = qt * 128 + wv * 32;
  const int qrb = wv * 32 + lr;

  bf16x8 bq[2][2];
#pragma unroll
  for (int fq = 0; fq < 2; ++fq)
#pragma unroll
    for (int ks = 0; ks < 2; ++ks)
      bq[fq][ks] = *(const bf16x8*)&Qsh[wv * 32 + fq * 16 + lr][ks * 32 + lg * 8];

  bf16x8 br[3][2];
#pragma unroll
  for (int jt = 0; jt < 3; ++jt)
#pragma unroll
    for (int ks = 0; ks < 2; ++ks)
      br[jt][ks] = *(const bf16x8*)&Rsh[jt * 16 + lr][ks * 32 + lg * 8];

  f32x4 gacc[2][3];
#pragma unroll
  for (int fq = 0; fq < 2; ++fq)
#pragma unroll
    for (int jt = 0; jt < 3; ++jt) {
      f32x4 g = MFMA16(bq[fq][0], br[jt][0], v4zero());
      gacc[fq][jt] = MFMA16(bq[fq][1], br[jt][1], g);
    }
  __syncthreads();

#pragma unroll
  for (int fq = 0; fq < 2; ++fq)
#pragma unroll
    for (int jt = 0; jt < 3; ++jt)
#pragma unroll
      for (int r = 0; r < 4; ++r)
        Gsh[jt * 16 + lr][(wv * 2 + fq) * 16 + lg * 4 + r] = gacc[fq][jt][r];
  __syncthreads();

  f32x4 byz[2][4];
#pragma unroll
  for (int fq = 0; fq < 2; ++fq) {
    const int q_r = qrb + fq * 16;
    const int qh_ = (q_r >> 3) & 7, qw_ = q_r & 7, qd_ = qt * 2 + (q_r >> 6);
#pragma unroll
    for (int fk = 0; fk < 4; ++fk) {
      f32x4 v;
#pragma unroll
      for (int i = 0; i < 4; ++i) {
        int kkl = fk * 16 + lg * 4 + i;
        v[i] = Gsh[15 + qh_ - (kkl >> 3) + 7][q_r] + Gsh[30 + qw_ - (kkl & 7) + 7][q_r];
      }
      byz[fq][fk] = v;
    }
    if (lg == 0) {
#pragma unroll
      for (int kt = 0; kt < 8; ++kt) rxT[kt][q_r] = Gsh[qd_ - kt + 7][q_r];
    }
  }
  __syncthreads();

#pragma unroll
  for (int r = 0; r < 2; ++r) {
    int ci = r * 256 + tid, row = ci >> 3, slot = ci & 7;
    *(bf16x8*)&Ksh[0][row][(slot ^ (row & 7)) * 8] = kreg[r];
    *(bf16x8*)&Vsh[0][row][(slot ^ (row & 7)) * 8] = vreg[r];
    kreg[r] = *(const bf16x8*)(Kb + (size_t)(64 + row) * 64 + slot * 8);
    vreg[r] = *(const bf16x8*)(Vb + (size_t)row * 512 + 64 + slot * 8);
  }
  __syncthreads();

  float rsum[2] = {0.f, 0.f};
  f32x4 oacc[2][4];
#pragma unroll
  for (int fq = 0; fq < 2; ++fq)
#pragma unroll
    for (int fc = 0; fc < 4; ++fc) oacc[fq][fc] = v4zero();

  for (int kt = 0; kt < 8; ++kt) {
    const int cur = kt & 1;
    bf16x8 ak[4][2];
#pragma unroll
    for (int fk = 0; fk < 4; ++fk) {
      const int row = fk * 16 + lr;
#pragma unroll
      for (int ks = 0; ks < 2; ++ks)
        ak[fk][ks] = *(const bf16x8*)&Ksh[cur][row][((ks * 4 + lg) ^ (row & 7)) * 8];
    }

    f32x4 sb[2][4];
#pragma unroll
    for (int fq = 0; fq < 2; ++fq) {
      const float rx = rxT[kt][qrb + fq * 16];
#pragma unroll
      for (int fk = 0; fk < 4; ++fk) {
        f32x4 s = MFMA16(ak[fk][0], bq[fq][0], v4zero());
        s = MFMA16(ak[fk][1], bq[fq][1], s);
        sb[fq][fk] = s * 0.125f + rx + byz[fq][fk];
      }
    }

#pragma unroll
    for (int fq = 0; fq < 2; ++fq) {
      float rs = 0.f;
#pragma unroll
      for (int fk = 0; fk < 4; ++fk)
#pragma unroll
        for (int i = 0; i < 4; ++i) {
          float p = __expf(sb[fq][fk][i]);
          sb[fq][fk][i] = p;
          rs += p;
        }
      rsum[fq] += rs;
    }

    bf16x8 pa[2][2];
#pragma unroll
    for (int fq = 0; fq < 2; ++fq)
#pragma unroll
      for (int h = 0; h < 2; ++h) {
#pragma unroll
        for (int j = 0; j < 4; ++j) {
          pa[fq][h][j] = (bf16_t)sb[fq][2 * h][j];
          pa[fq][h][4 + j] = (bf16_t)sb[fq][2 * h + 1][j];
        }
      }

#pragma unroll
    for (int h = 0; h < 2; ++h)
#pragma unroll
      for (int fc2 = 0; fc2 < 4; ++fc2) {
        const int row = fc2 * 16 + lr;
        const int c0 = (((h * 4 + (lg >> 1)) ^ (row & 7)) * 8) + (lg & 1) * 4;
        const int c1 = (((h * 4 + 2 + (lg >> 1)) ^ (row & 7)) * 8) + (lg & 1) * 4;
        bf16x4 v0 = *(const bf16x4*)&Vsh[cur][row][c0];
        bf16x4 v1 = *(const bf16x4*)&Vsh[cur][row][c1];
        bf16x8 bv;
#pragma unroll
        for (int j = 0; j < 4; ++j) {
          bv[j] = v0[j];
          bv[4 + j] = v1[j];
        }
#pragma unroll
        for (int fq = 0; fq < 2; ++fq)
          oacc[fq][fc2] = MFMA16(pa[fq][h], bv, oacc[fq][fc2]);
      }

    if (kt < 7) {
#pragma unroll
      for (int r = 0; r < 2; ++r) {
        int ci = r * 256 + tid, row = ci >> 3, slot = ci & 7;
        *(bf16x8*)&Ksh[cur ^ 1][row][(slot ^ (row & 7)) * 8] = kreg[r];
        *(bf16x8*)&Vsh[cur ^ 1][row][(slot ^ (row & 7)) * 8] = vreg[r];
        if (kt < 6) {
          kreg[r] = *(const bf16x8*)(Kb + (size_t)((kt + 2) * 64 + row) * 64 + slot * 8);
          vreg[r] = *(const bf16x8*)(Vb + (size_t)row * 512 + (kt + 2) * 64 + slot * 8);
        }
      }
    }
    __syncthreads();
  }

#pragma unroll
  for (int fq = 0; fq < 2; ++fq) {
    rsum[fq] += __shfl_xor(rsum[fq], 16);
    rsum[fq] += __shfl_xor(rsum[fq], 32);
  }
  f32x4 linv[2];
#pragma unroll
  for (int fq = 0; fq < 2; ++fq)
#pragma unroll
    for (int i = 0; i < 4; ++i)
      linv[fq][i] = 1.0f / __shfl(rsum[fq], lg * 4 + i);

#pragma unroll
  for (int fq = 0; fq < 2; ++fq)
#pragma unroll
    for (int fc2 = 0; fc2 < 4; ++fc2) {
      size_t base = ((size_t)win * 512 + qrow0 + fq * 16 + lg * 4) * 384 + hh * 64 + fc2 * 16 + lr;
#pragma unroll
      for (int i = 0; i < 4; ++i)
        ao[base + (size_t)i * 384] = (bf16_t)(oacc[fq][fc2][i] * linv[fq][i]);
    }
}

// ---------------- kernel 3: output projection, depth-2 dbuf (named regs) ----
__global__ __launch_bounds__(256) void proj_kernel(
    const bf16_t* __restrict__ ain, const float* __restrict__ w,
    const float* __restrict__ bias, float* __restrict__ out) {
  __shared__ __align__(16) char smem[40960];
  bf16_t(*As)[128][40] = (bf16_t(*)[128][40])smem;
  bf16_t(*Bs)[128][40] = (bf16_t(*)[128][40])(smem + 20480);

  const int tid = threadIdx.x;
  const int lane = tid & 63, wv = tid >> 6;
  const int m0 = blockIdx.x * 128, n0 = blockIdx.y * 128;

  const int arow = tid >> 1, aseg = tid & 1;
  const bf16_t* asrc = ain + (size_t)(m0 + arow) * 384 + aseg * 16;
  const int bn = tid & 127, bks = (tid >> 7) * 16;
  const float* bsrc = w + (size_t)bks * 384 + n0 + bn;

  const int wr = (wv >> 1) * 64, wc = (wv & 1) * 64;
  const int lr = lane & 15, lk = (lane >> 4) * 8;

  f32x4 acc[4][4];
#pragma unroll
  for (int fr = 0; fr < 4; ++fr)
#pragma unroll
    for (int fc = 0; fc < 4; ++fc) acc[fr][fc] = v4zero();

  bf16x8 a0r, a1r;
  float bfr[16];

#define PLOAD(kt)                                                  \
  {                                                                \
    a0r = *(const bf16x8*)(asrc + (kt)*32);                        \
    a1r = *(const bf16x8*)(asrc + (kt)*32 + 8);                    \
    _Pragma("unroll") for (int i = 0; i < 16; ++i)                 \
        bfr[i] = bsrc[(size_t)((kt)*32 + i) * 384];                \
  }

#define PSTAGE(buf)                                                \
  {                                                                \
    bf16x8 b0, b1;                                                 \
    _Pragma("unroll") for (int i = 0; i < 8; ++i) {                \
      b0[i] = (bf16_t)bfr[i];                                      \
      b1[i] = (bf16_t)bfr[8 + i];                                  \
    }                                                              \
    *(bf16x8*)&As[buf][arow][aseg * 16] = a0r;                     \
    *(bf16x8*)&As[buf][arow][aseg * 16 + 8] = a1r;                 \
    *(bf16x8*)&Bs[buf][bn][bks] = b0;                              \
    *(bf16x8*)&Bs[buf][bn][bks + 8] = b1;                          \
  }

  PLOAD(0);
  PSTAGE(0);
  PLOAD(1);
  __syncthreads();

  for (int kt = 0; kt < 12; ++kt) {
    const int cur = kt & 1;
    bf16x8 af[4], bfv[4];
#pragma unroll
    for (int fr = 0; fr < 4; ++fr) af[fr] = *(const bf16x8*)&As[cur][wr + fr * 16 + lr][lk];
#pragma unroll
    for (int fc = 0; fc < 4; ++fc) bfv[fc] = *(const bf16x8*)&Bs[cur][wc + fc * 16 + lr][lk];
#pragma unroll
    for (int fr = 0; fr < 4; ++fr)
#pragma unroll
      for (int fc = 0; fc < 4; ++fc)
        acc[fr][fc] = MFMA16(af[fr], bfv[fc], acc[fr][fc]);
    if (kt < 11) {
      PSTAGE(cur ^ 1);
      if (kt < 10) PLOAD(kt + 2);
    }
    __syncthreads();
  }
#undef PLOAD
#undef PSTAGE

#pragma unroll
  for (int fc = 0; fc < 4; ++fc) {
    const int col = n0 + wc + fc * 16 + lr;
    const float bc = bias[col];
#pragma unroll
    for (int fr = 0; fr < 4; ++fr) {
      const int m = m0 + wr + fr * 16 + (lane >> 4) * 4;
#pragma unroll
      for (int r = 0; r < 4; ++r)
        out[(size_t)xrow_of(m + r) * 384 + col] = acc[fr][fc][r] + bc;
    }
  }
}

extern "C" void kernel_launch(void* const* d_in, const int* in_sizes, int n_in,
                              void* d_out, int out_size, void* d_ws, size_t ws_size,
                              hipStream_t stream) {
  (void)in_sizes; (void)n_in; (void)out_size;
  const float* x = (const float*)d_in[0];
  const float* qkv_w = (const float*)d_in[1];
  const float* qkv_b = (const float*)d_in[2];
  const float* proj_w = (const float*)d_in[3];
  const float* proj_b = (const float*)d_in[4];
  const float* rpx = (const float*)d_in[5];
  const float* rpy = (const float*)d_in[6];
  const float* rpz = (const float*)d_in[7];
  float* out = (float*)d_out;

  const size_t NE = 6291456;  // 32*6*512*64 = 16384*384
  if (ws_size < NE * 4 * sizeof(bf16_t)) return;
  bf16_t* qg = (bf16_t*)d_ws;
  bf16_t* kg = qg + NE;
  bf16_t* vtg = kg + NE;
  bf16_t* ao = vtg + NE;

  qkv_kernel<<<dim3(128, 9), 256, 0, stream>>>(x, qkv_w, qkv_b, qg, kg, vtg);
  attn_kernel<<<dim3(6, 32, 4), 256, 0, stream>>>(qg, kg, vtg, rpx, rpy, rpz, ao);
  proj_kernel<<<dim3(128, 3), 256, 0, stream>>>(ao, proj_w, proj_b, out);
}

// Round 18
// 88.478 us; speedup vs baseline: 1.8058x; 1.0645x over previous
//
#include <hip/hip_runtime.h>
#include <hip/hip_bf16.h>

typedef __bf16 bf16_t;
typedef __bf16 bf16x8 __attribute__((ext_vector_type(8)));
typedef __bf16 bf16x4 __attribute__((ext_vector_type(4)));
typedef float f32x4 __attribute__((ext_vector_type(4)));

#define MFMA16(a, b, c) __builtin_amdgcn_mfma_f32_16x16x32_bf16((a), (b), (c), 0, 0, 0)

__device__ __forceinline__ f32x4 v4zero() {
  f32x4 z = {0.f, 0.f, 0.f, 0.f};
  return z;
}

// window-partition row mapping: m = win*512 + t  ->  row in x [B*4096]
__device__ __forceinline__ int xrow_of(int m) {
  int win = m >> 9, t = m & 511;
  int b = win >> 3, d1 = (win >> 2) & 1, h1 = (win >> 1) & 1, w1 = win & 1;
  int d2 = t >> 6, h2 = (t >> 3) & 7, w2 = t & 7;
  return (b << 12) | ((d1 * 8 + d2) << 8) | ((h1 * 8 + h2) << 4) | (w1 * 8 + w2);
}

// ---------------- kernel 1: QKV projection, depth-2 dbuf (round-15 best) ----
// grid (128, 9), block 256. One output type per block (n0/384).
__global__ __launch_bounds__(256) void qkv_kernel(
    const float* __restrict__ x, const float* __restrict__ w,
    const float* __restrict__ bias, bf16_t* __restrict__ qg,
    bf16_t* __restrict__ kg, bf16_t* __restrict__ vtg) {
  __shared__ __align__(16) char smem[40960];
  bf16_t(*As)[128][40] = (bf16_t(*)[128][40])smem;            // [2][128][40]
  bf16_t(*Bs)[128][40] = (bf16_t(*)[128][40])(smem + 20480);  // [2][128][40]
  bf16_t(*Csh)[136] = (bf16_t(*)[136])smem;                   // epilogue overlay

  const int tid = threadIdx.x;
  const int lane = tid & 63, wv = tid >> 6;
  const int m0 = blockIdx.x * 128, n0 = blockIdx.y * 128;

  const int arow = tid >> 1, aseg = tid & 1;
  const float* asrc = x + (size_t)xrow_of(m0 + arow) * 384 + aseg * 16;
  const int bn = tid & 127, bks = (tid >> 7) * 16;
  const float* bsrc = w + (size_t)bks * 1152 + n0 + bn;

  const int wr = (wv >> 1) * 64, wc = (wv & 1) * 64;
  const int lr = lane & 15, lg = lane >> 4, lk = lg * 8;

  f32x4 acc[4][4];
#pragma unroll
  for (int fr = 0; fr < 4; ++fr)
#pragma unroll
    for (int fc = 0; fc < 4; ++fc) acc[fr][fc] = v4zero();

  f32x4 afr[4];
  float bfr[16];

#define LOAD_TILE(kt)                                              \
  {                                                                \
    _Pragma("unroll") for (int i = 0; i < 4; ++i)                  \
        afr[i] = *(const f32x4*)(asrc + (kt)*32 + i * 4);          \
    _Pragma("unroll") for (int i = 0; i < 16; ++i)                 \
        bfr[i] = bsrc[(size_t)((kt)*32 + i) * 1152];               \
  }

#define STAGE_TILE(buf)                                            \
  {                                                                \
    bf16x8 a0, a1, b0, b1;                                         \
    _Pragma("unroll") for (int i = 0; i < 4; ++i) {                \
      a0[i] = (bf16_t)afr[0][i];                                   \
      a0[4 + i] = (bf16_t)afr[1][i];                               \
      a1[i] = (bf16_t)afr[2][i];                                   \
      a1[4 + i] = (bf16_t)afr[3][i];                               \
    }                                                              \
    _Pragma("unroll") for (int i = 0; i < 8; ++i) {                \
      b0[i] = (bf16_t)bfr[i];                                      \
      b1[i] = (bf16_t)bfr[8 + i];                                  \
    }                                                              \
    *(bf16x8*)&As[buf][arow][aseg * 16] = a0;                      \
    *(bf16x8*)&As[buf][arow][aseg * 16 + 8] = a1;                  \
    *(bf16x8*)&Bs[buf][bn][bks] = b0;                              \
    *(bf16x8*)&Bs[buf][bn][bks + 8] = b1;                          \
  }

  LOAD_TILE(0);
  STAGE_TILE(0);
  LOAD_TILE(1);
  __syncthreads();

  for (int kt = 0; kt < 12; ++kt) {
    const int cur = kt & 1;
    bf16x8 af[4], bfv[4];
#pragma unroll
    for (int fr = 0; fr < 4; ++fr) af[fr] = *(const bf16x8*)&As[cur][wr + fr * 16 + lr][lk];
#pragma unroll
    for (int fc = 0; fc < 4; ++fc) bfv[fc] = *(const bf16x8*)&Bs[cur][wc + fc * 16 + lr][lk];
#pragma unroll
    for (int fr = 0; fr < 4; ++fr)
#pragma unroll
      for (int fc = 0; fc < 4; ++fc)
        acc[fr][fc] = MFMA16(af[fr], bfv[fc], acc[fr][fc]);
    if (kt < 11) {
      STAGE_TILE(cur ^ 1);
      if (kt < 10) LOAD_TILE(kt + 2);
    }
    __syncthreads();
  }
#undef LOAD_TILE
#undef STAGE_TILE

  const int type = n0 / 384;
  if (type == 2) {
    // V: store transposed [64][512], direct bf16x4 (t-contiguous)
#pragma unroll
    for (int fc = 0; fc < 4; ++fc) {
      const int col = n0 + wc + fc * 16 + lr;
      const float bc = bias[col];
      const int cc = col - 768, hh = cc >> 6, c = cc & 63;
#pragma unroll
      for (int fr = 0; fr < 4; ++fr) {
        const int m = m0 + wr + fr * 16 + lg * 4;
        const int win = m >> 9, t = m & 511;
        bf16x4 pk;
#pragma unroll
        for (int r = 0; r < 4; ++r) pk[r] = (bf16_t)(acc[fr][fc][r] + bc);
        *(bf16x4*)(vtg + ((size_t)(win * 6 + hh) * 64 + c) * 512 + t) = pk;
      }
    }
  } else {
    // Q/K: transpose through LDS, write coalesced bf16x8 rows
#pragma unroll
    for (int fc = 0; fc < 4; ++fc) {
      const int col = n0 + wc + fc * 16 + lr;
      const float bc = bias[col];
#pragma unroll
      for (int fr = 0; fr < 4; ++fr)
#pragma unroll
        for (int r = 0; r < 4; ++r)
          Csh[wr + fr * 16 + lg * 4 + r][wc + fc * 16 + lr] = (bf16_t)(acc[fr][fc][r] + bc);
    }
    __syncthreads();
    const int mloc = tid >> 1, half = tid & 1;
    const int hh2 = ((n0 - type * 384) >> 6) + half;
    const int m = m0 + mloc, win = m >> 9, t = m & 511;
    bf16_t* dst = (type == 0 ? qg : kg) + ((size_t)(win * 6 + hh2) * 512 + t) * 64;
#pragma unroll
    for (int j = 0; j < 8; ++j)
      *(bf16x8*)(dst + j * 8) = *(const bf16x8*)&Csh[mloc][half * 64 + j * 8];
  }
}

// ---------------- kernel 2: attention (unchanged) ---------------------------
__global__ __launch_bounds__(256) void attn_kernel(
    const bf16_t* __restrict__ qg, const bf16_t* __restrict__ kg,
    const bf16_t* __restrict__ vtg, const float* __restrict__ rpx,
    const float* __restrict__ rpy, const float* __restrict__ rpz,
    bf16_t* __restrict__ ao) {
  __shared__ __align__(16) char smem[32768];   // phase union
  __shared__ __align__(16) float rxT[8][132];  // persistent rx strip
  const int tid = threadIdx.x, lane = tid & 63, wv = tid >> 6;
  const int hh = blockIdx.x, win = blockIdx.y, qt = blockIdx.z;
  const int wh = win * 6 + hh;
  const bf16_t* Qb = qg + (size_t)wh * 32768 + (size_t)qt * 8192;
  const bf16_t* Kb = kg + (size_t)wh * 32768;
  const bf16_t* Vb = vtg + (size_t)wh * 32768;  // transposed [64][512]

  bf16_t(*Qsh)[68] = (bf16_t(*)[68])smem;
  bf16_t(*Rsh)[68] = (bf16_t(*)[68])(smem + 17408);
  float(*Gsh)[132] = (float(*)[132])smem;
  bf16_t(*Ksh)[64][64] = (bf16_t(*)[64][64])smem;
  bf16_t(*Vsh)[64][64] = (bf16_t(*)[64][64])(smem + 16384);

  for (int i = tid; i < 1024; i += 256) {
    int row = i >> 3, slot = i & 7;
    *(bf16x8*)&Qsh[row][slot * 8] = *(const bf16x8*)(Qb + row * 64 + slot * 8);
  }
  for (int i = tid; i < 360; i += 256) {
    int row = i >> 3, slot = i & 7;
    int axis = row / 15, j = row - axis * 15;
    const float* RP = (axis == 0) ? rpx : (axis == 1) ? rpy : rpz;
    f32x4 r0 = *(const f32x4*)(RP + j * 64 + slot * 8);
    f32x4 r1 = *(const f32x4*)(RP + j * 64 + slot * 8 + 4);
    bf16x8 p;
#pragma unroll
    for (int jj = 0; jj < 4; ++jj) {
      p[jj] = (bf16_t)r0[jj];
      p[4 + jj] = (bf16_t)r1[jj];
    }
    *(bf16x8*)&Rsh[row][slot * 8] = p;
  }
  bf16x8 kreg[2], vreg[2];
#pragma unroll
  for (int r = 0; r < 2; ++r) {
    int ci = r * 256 + tid, row = ci >> 3, slot = ci & 7;
    kreg[r] = *(const bf16x8*)(Kb + (size_t)row * 64 + slot * 8);
    vreg[r] = *(const bf16x8*)(Vb + (size_t)row * 512 + slot * 8);
  }
  __syncthreads();

  const int lr = lane & 15, lg = lane >> 4;
  const int qrow0 = qt * 128 + wv * 32;
  const int qrb = wv * 32 + lr;

  bf16x8 bq[2][2];
#pragma unroll
  for (int fq = 0; fq < 2; ++fq)
#pragma unroll
    for (int ks = 0; ks < 2; ++ks)
      bq[fq][ks] = *(const bf16x8*)&Qsh[wv * 32 + fq * 16 + lr][ks * 32 + lg * 8];

  bf16x8 br[3][2];
#pragma unroll
  for (int jt = 0; jt < 3; ++jt)
#pragma unroll
    for (int ks = 0; ks < 2; ++ks)
      br[jt][ks] = *(const bf16x8*)&Rsh[jt * 16 + lr][ks * 32 + lg * 8];

  f32x4 gacc[2][3];
#pragma unroll
  for (int fq = 0; fq < 2; ++fq)
#pragma unroll
    for (int jt = 0; jt < 3; ++jt) {
      f32x4 g = MFMA16(bq[fq][0], br[jt][0], v4zero());
      gacc[fq][jt] = MFMA16(bq[fq][1], br[jt][1], g);
    }
  __syncthreads();

#pragma unroll
  for (int fq = 0; fq < 2; ++fq)
#pragma unroll
    for (int jt = 0; jt < 3; ++jt)
#pragma unroll
      for (int r = 0; r < 4; ++r)
        Gsh[jt * 16 + lr][(wv * 2 + fq) * 16 + lg * 4 + r] = gacc[fq][jt][r];
  __syncthreads();

  f32x4 byz[2][4];
#pragma unroll
  for (int fq = 0; fq < 2; ++fq) {
    const int q_r = qrb + fq * 16;
    const int qh_ = (q_r >> 3) & 7, qw_ = q_r & 7, qd_ = qt * 2 + (q_r >> 6);
#pragma unroll
    for (int fk = 0; fk < 4; ++fk) {
      f32x4 v;
#pragma unroll
      for (int i = 0; i < 4; ++i) {
        int kkl = fk * 16 + lg * 4 + i;
        v[i] = Gsh[15 + qh_ - (kkl >> 3) + 7][q_r] + Gsh[30 + qw_ - (kkl & 7) + 7][q_r];
      }
      byz[fq][fk] = v;
    }
    if (lg == 0) {
#pragma unroll
      for (int kt = 0; kt < 8; ++kt) rxT[kt][q_r] = Gsh[qd_ - kt + 7][q_r];
    }
  }
  __syncthreads();

#pragma unroll
  for (int r = 0; r < 2; ++r) {
    int ci = r * 256 + tid, row = ci >> 3, slot = ci & 7;
    *(bf16x8*)&Ksh[0][row][(slot ^ (row & 7)) * 8] = kreg[r];
    *(bf16x8*)&Vsh[0][row][(slot ^ (row & 7)) * 8] = vreg[r];
    kreg[r] = *(const bf16x8*)(Kb + (size_t)(64 + row) * 64 + slot * 8);
    vreg[r] = *(const bf16x8*)(Vb + (size_t)row * 512 + 64 + slot * 8);
  }
  __syncthreads();

  float rsum[2] = {0.f, 0.f};
  f32x4 oacc[2][4];
#pragma unroll
  for (int fq = 0; fq < 2; ++fq)
#pragma unroll
    for (int fc = 0; fc < 4; ++fc) oacc[fq][fc] = v4zero();

  for (int kt = 0; kt < 8; ++kt) {
    const int cur = kt & 1;
    bf16x8 ak[4][2];
#pragma unroll
    for (int fk = 0; fk < 4; ++fk) {
      const int row = fk * 16 + lr;
#pragma unroll
      for (int ks = 0; ks < 2; ++ks)
        ak[fk][ks] = *(const bf16x8*)&Ksh[cur][row][((ks * 4 + lg) ^ (row & 7)) * 8];
    }

    f32x4 sb[2][4];
#pragma unroll
    for (int fq = 0; fq < 2; ++fq) {
      const float rx = rxT[kt][qrb + fq * 16];
#pragma unroll
      for (int fk = 0; fk < 4; ++fk) {
        f32x4 s = MFMA16(ak[fk][0], bq[fq][0], v4zero());
        s = MFMA16(ak[fk][1], bq[fq][1], s);
        sb[fq][fk] = s * 0.125f + rx + byz[fq][fk];
      }
    }

#pragma unroll
    for (int fq = 0; fq < 2; ++fq) {
      float rs = 0.f;
#pragma unroll
      for (int fk = 0; fk < 4; ++fk)
#pragma unroll
        for (int i = 0; i < 4; ++i) {
          float p = __expf(sb[fq][fk][i]);
          sb[fq][fk][i] = p;
          rs += p;
        }
      rsum[fq] += rs;
    }

    bf16x8 pa[2][2];
#pragma unroll
    for (int fq = 0; fq < 2; ++fq)
#pragma unroll
      for (int h = 0; h < 2; ++h) {
#pragma unroll
        for (int j = 0; j < 4; ++j) {
          pa[fq][h][j] = (bf16_t)sb[fq][2 * h][j];
          pa[fq][h][4 + j] = (bf16_t)sb[fq][2 * h + 1][j];
        }
      }

#pragma unroll
    for (int h = 0; h < 2; ++h)
#pragma unroll
      for (int fc2 = 0; fc2 < 4; ++fc2) {
        const int row = fc2 * 16 + lr;
        const int c0 = (((h * 4 + (lg >> 1)) ^ (row & 7)) * 8) + (lg & 1) * 4;
        const int c1 = (((h * 4 + 2 + (lg >> 1)) ^ (row & 7)) * 8) + (lg & 1) * 4;
        bf16x4 v0 = *(const bf16x4*)&Vsh[cur][row][c0];
        bf16x4 v1 = *(const bf16x4*)&Vsh[cur][row][c1];
        bf16x8 bv;
#pragma unroll
        for (int j = 0; j < 4; ++j) {
          bv[j] = v0[j];
          bv[4 + j] = v1[j];
        }
#pragma unroll
        for (int fq = 0; fq < 2; ++fq)
          oacc[fq][fc2] = MFMA16(pa[fq][h], bv, oacc[fq][fc2]);
      }

    if (kt < 7) {
#pragma unroll
      for (int r = 0; r < 2; ++r) {
        int ci = r * 256 + tid, row = ci >> 3, slot = ci & 7;
        *(bf16x8*)&Ksh[cur ^ 1][row][(slot ^ (row & 7)) * 8] = kreg[r];
        *(bf16x8*)&Vsh[cur ^ 1][row][(slot ^ (row & 7)) * 8] = vreg[r];
        if (kt < 6) {
          kreg[r] = *(const bf16x8*)(Kb + (size_t)((kt + 2) * 64 + row) * 64 + slot * 8);
          vreg[r] = *(const bf16x8*)(Vb + (size_t)row * 512 + (kt + 2) * 64 + slot * 8);
        }
      }
    }
    __syncthreads();
  }

#pragma unroll
  for (int fq = 0; fq < 2; ++fq) {
    rsum[fq] += __shfl_xor(rsum[fq], 16);
    rsum[fq] += __shfl_xor(rsum[fq], 32);
  }
  f32x4 linv[2];
#pragma unroll
  for (int fq = 0; fq < 2; ++fq)
#pragma unroll
    for (int i = 0; i < 4; ++i)
      linv[fq][i] = 1.0f / __shfl(rsum[fq], lg * 4 + i);

#pragma unroll
  for (int fq = 0; fq < 2; ++fq)
#pragma unroll
    for (int fc2 = 0; fc2 < 4; ++fc2) {
      size_t base = ((size_t)win * 512 + qrow0 + fq * 16 + lg * 4) * 384 + hh * 64 + fc2 * 16 + lr;
#pragma unroll
      for (int i = 0; i < 4; ++i)
        ao[base + (size_t)i * 384] = (bf16_t)(oacc[fq][fc2][i] * linv[fq][i]);
    }
}

// ---------------- kernel 3: output projection, depth-2 dbuf (named regs) ----
__global__ __launch_bounds__(256) void proj_kernel(
    const bf16_t* __restrict__ ain, const float* __restrict__ w,
    const float* __restrict__ bias, float* __restrict__ out) {
  __shared__ __align__(16) char smem[40960];
  bf16_t(*As)[128][40] = (bf16_t(*)[128][40])smem;
  bf16_t(*Bs)[128][40] = (bf16_t(*)[128][40])(smem + 20480);

  const int tid = threadIdx.x;
  const int lane = tid & 63, wv = tid >> 6;
  const int m0 = blockIdx.x * 128, n0 = blockIdx.y * 128;

  const int arow = tid >> 1, aseg = tid & 1;
  const bf16_t* asrc = ain + (size_t)(m0 + arow) * 384 + aseg * 16;
  const int bn = tid & 127, bks = (tid >> 7) * 16;
  const float* bsrc = w + (size_t)bks * 384 + n0 + bn;

  const int wr = (wv >> 1) * 64, wc = (wv & 1) * 64;
  const int lr = lane & 15, lk = (lane >> 4) * 8;

  f32x4 acc[4][4];
#pragma unroll
  for (int fr = 0; fr < 4; ++fr)
#pragma unroll
    for (int fc = 0; fc < 4; ++fc) acc[fr][fc] = v4zero();

  bf16x8 a0r, a1r;
  float bfr[16];

#define PLOAD(kt)                                                  \
  {                                                                \
    a0r = *(const bf16x8*)(asrc + (kt)*32);                        \
    a1r = *(const bf16x8*)(asrc + (kt)*32 + 8);                    \
    _Pragma("unroll") for (int i = 0; i < 16; ++i)                 \
        bfr[i] = bsrc[(size_t)((kt)*32 + i) * 384];                \
  }

#define PSTAGE(buf)                                                \
  {                                                                \
    bf16x8 b0, b1;                                                 \
    _Pragma("unroll") for (int i = 0; i < 8; ++i) {                \
      b0[i] = (bf16_t)bfr[i];                                      \
      b1[i] = (bf16_t)bfr[8 + i];                                  \
    }                                                              \
    *(bf16x8*)&As[buf][arow][aseg * 16] = a0r;                     \
    *(bf16x8*)&As[buf][arow][aseg * 16 + 8] = a1r;                 \
    *(bf16x8*)&Bs[buf][bn][bks] = b0;                              \
    *(bf16x8*)&Bs[buf][bn][bks + 8] = b1;                          \
  }

  PLOAD(0);
  PSTAGE(0);
  PLOAD(1);
  __syncthreads();

  for (int kt = 0; kt < 12; ++kt) {
    const int cur = kt & 1;
    bf16x8 af[4], bfv[4];
#pragma unroll
    for (int fr = 0; fr < 4; ++fr) af[fr] = *(const bf16x8*)&As[cur][wr + fr * 16 + lr][lk];
#pragma unroll
    for (int fc = 0; fc < 4; ++fc) bfv[fc] = *(const bf16x8*)&Bs[cur][wc + fc * 16 + lr][lk];
#pragma unroll
    for (int fr = 0; fr < 4; ++fr)
#pragma unroll
      for (int fc = 0; fc < 4; ++fc)
        acc[fr][fc] = MFMA16(af[fr], bfv[fc], acc[fr][fc]);
    if (kt < 11) {
      PSTAGE(cur ^ 1);
      if (kt < 10) PLOAD(kt + 2);
    }
    __syncthreads();
  }
#undef PLOAD
#undef PSTAGE

#pragma unroll
  for (int fc = 0; fc < 4; ++fc) {
    const int col = n0 + wc + fc * 16 + lr;
    const float bc = bias[col];
#pragma unroll
    for (int fr = 0; fr < 4; ++fr) {
      const int m = m0 + wr + fr * 16 + (lane >> 4) * 4;
#pragma unroll
      for (int r = 0; r < 4; ++r)
        out[(size_t)xrow_of(m + r) * 384 + col] = acc[fr][fc][r] + bc;
    }
  }
}

extern "C" void kernel_launch(void* const* d_in, const int* in_sizes, int n_in,
                              void* d_out, int out_size, void* d_ws, size_t ws_size,
                              hipStream_t stream) {
  (void)in_sizes; (void)n_in; (void)out_size;
  const float* x = (const float*)d_in[0];
  const float* qkv_w = (const float*)d_in[1];
  const float* qkv_b = (const float*)d_in[2];
  const float* proj_w = (const float*)d_in[3];
  const float* proj_b = (const float*)d_in[4];
  const float* rpx = (const float*)d_in[5];
  const float* rpy = (const float*)d_in[6];
  const float* rpz = (const float*)d_in[7];
  float* out = (float*)d_out;

  const size_t NE = 6291456;  // 32*6*512*64 = 16384*384
  if (ws_size < NE * 4 * sizeof(bf16_t)) return;
  bf16_t* qg = (bf16_t*)d_ws;
  bf16_t* kg = qg + NE;
  bf16_t* vtg = kg + NE;
  bf16_t* ao = vtg + NE;

  qkv_kernel<<<dim3(128, 9), 256, 0, stream>>>(x, qkv_w, qkv_b, qg, kg, vtg);
  attn_kernel<<<dim3(6, 32, 4), 256, 0, stream>>>(qg, kg, vtg, rpx, rpy, rpz, ao);
  proj_kernel<<<dim3(128, 3), 256, 0, stream>>>(ao, proj_w, proj_b, out);
}